// Round 6
// baseline (172.298 us; speedup 1.0000x reference)
//
#include <hip/hip_runtime.h>
#include <hip/hip_bf16.h>
#include <cstddef>

// Dims fixed by reference: B=2, S=2048, H=1024, NH=4, DH=256
constexpr int Bx = 2, Sx = 2048, Hx = 1024, NHx = 4, DHx = 256;
constexpr float RSQ = 0.0625f;   // 1/sqrt(256)

typedef __attribute__((ext_vector_type(8))) short    bf16x8;
typedef __attribute__((ext_vector_type(4))) float    f32x4;

__device__ __forceinline__ float logsigf(float x) {
  return (x >= 0.0f) ? -log1pf(expf(-x)) : x - log1pf(expf(x));
}
__device__ __forceinline__ unsigned short f2bf(float x) {  // RNE f32->bf16
  unsigned u = __builtin_bit_cast(unsigned, x);
  u = (u + 0x7fffu + ((u >> 16) & 1u)) >> 16;
  return (unsigned short)u;
}
__device__ __forceinline__ unsigned pk2bf(float a, float b) {
  return (unsigned)f2bf(a) | ((unsigned)f2bf(b) << 16);
}

// ---------- K1: gates (ig/fg) + bf16 side-copies of Q,K ---------------------
// 16 rows per block (512 thr = 8 waves, 2 rows/wave) to amortize W reads.
__global__ __launch_bounds__(512)
void gates_kernel(const float* __restrict__ q, const float* __restrict__ k,
                  const float* __restrict__ v,
                  const float* __restrict__ wi, const float* __restrict__ bi,
                  const float* __restrict__ wf, const float* __restrict__ bf,
                  float* __restrict__ ig, float* __restrict__ fg,
                  unsigned short* __restrict__ Qb, unsigned short* __restrict__ Kb)
{
  const int w = threadIdx.x >> 6, l = threadIdx.x & 63;
  const int bs0 = blockIdx.x * 16;
  const int bsr0 = bs0 + w * 2, bsr1 = bsr0 + 1;
  float p[2][8];
#pragma unroll
  for (int rr = 0; rr < 2; ++rr)
#pragma unroll
    for (int g2 = 0; g2 < 8; ++g2) p[rr][g2] = 0.f;

#pragma unroll
  for (int chunk = 0; chunk < 12; ++chunk) {
    const int idx = l * 4 + chunk * 256;     // 0..3071
    const float* src; int off;
    if (idx < 1024)       { src = q; off = idx; }
    else if (idx < 2048)  { src = k; off = idx - 1024; }
    else                  { src = v; off = idx - 2048; }
    float4 g0 = *(const float4*)(src + (size_t)bsr0 * Hx + off);
    float4 g1 = *(const float4*)(src + (size_t)bsr1 * Hx + off);
#pragma unroll
    for (int h = 0; h < 4; ++h) {
      float4 wiv = *(const float4*)(wi + h * 3 * Hx + idx);
      float4 wfv = *(const float4*)(wf + h * 3 * Hx + idx);
      p[0][h]     += g0.x*wiv.x + g0.y*wiv.y + g0.z*wiv.z + g0.w*wiv.w;
      p[1][h]     += g1.x*wiv.x + g1.y*wiv.y + g1.z*wiv.z + g1.w*wiv.w;
      p[0][4 + h] += g0.x*wfv.x + g0.y*wfv.y + g0.z*wfv.z + g0.w*wfv.w;
      p[1][4 + h] += g1.x*wfv.x + g1.y*wfv.y + g1.z*wfv.z + g1.w*wfv.w;
    }
    if (idx < 2048) {
      unsigned short* dst = (idx < 1024) ? Qb : Kb;
      const int hh = off >> 8, d = off & 255;
      const int b0 = bsr0 >> 11, s0p = bsr0 & 2047;
      const int b1 = bsr1 >> 11, s1p = bsr1 & 2047;
      ushort4 o0; o0.x=f2bf(g0.x); o0.y=f2bf(g0.y); o0.z=f2bf(g0.z); o0.w=f2bf(g0.w);
      ushort4 o1; o1.x=f2bf(g1.x); o1.y=f2bf(g1.y); o1.z=f2bf(g1.z); o1.w=f2bf(g1.w);
      *(ushort4*)(dst + ((size_t)(b0 * NHx + hh) * Sx + s0p) * DHx + d) = o0;
      *(ushort4*)(dst + ((size_t)(b1 * NHx + hh) * Sx + s1p) * DHx + d) = o1;
    }
  }
#pragma unroll
  for (int rr = 0; rr < 2; ++rr)
#pragma unroll
    for (int g2 = 0; g2 < 8; ++g2) {
      float x = p[rr][g2];
      x += __shfl_xor(x, 1);  x += __shfl_xor(x, 2);  x += __shfl_xor(x, 4);
      x += __shfl_xor(x, 8);  x += __shfl_xor(x, 16); x += __shfl_xor(x, 32);
      p[rr][g2] = x;
    }
  if (l == 0) {
#pragma unroll
    for (int rr = 0; rr < 2; ++rr) {
      const int bs = bs0 + w * 2 + rr;
      const int b = bs >> 11, spos = bs & 2047;
#pragma unroll
      for (int h = 0; h < 4; ++h) {
        ig[(size_t)(b * NHx + h) * Sx + spos] = p[rr][h] + bi[h];
        fg[(size_t)(b * NHx + h) * Sx + spos] = p[rr][4 + h] + bf[h];
      }
    }
  }
}

// ---------- K2: per-(b,h) scan: a[], M[], exp(-m)[] -------------------------
__global__ __launch_bounds__(256)
void scan_kernel(const float* __restrict__ ig, const float* __restrict__ fg,
                 float* __restrict__ av, float* __restrict__ Mv,
                 float* __restrict__ nfv)
{
  const int bh = blockIdx.x;
  const int t  = threadIdx.x;
  const size_t base = (size_t)bh * Sx;
  const int s0 = t * 8;
  float4 f0 = *(const float4*)(fg + base + s0);
  float4 f1 = *(const float4*)(fg + base + s0 + 4);
  float4 g0 = *(const float4*)(ig + base + s0);
  float4 g1 = *(const float4*)(ig + base + s0 + 4);
  float xf[8] = {f0.x,f0.y,f0.z,f0.w,f1.x,f1.y,f1.z,f1.w};
  float xi[8] = {g0.x,g0.y,g0.z,g0.w,g1.x,g1.y,g1.z,g1.w};
  float ps[8];
  float run = 0.0f;
#pragma unroll
  for (int i = 0; i < 8; ++i) { run += logsigf(xf[i]); ps[i] = run; }
  __shared__ float ssum[256];
  __shared__ float smax[256];
  ssum[t] = run;
  __syncthreads();
  for (int st = 1; st < 256; st <<= 1) {
    float addv = (t >= st) ? ssum[t - st] : 0.0f;
    __syncthreads();
    ssum[t] += addv;
    __syncthreads();
  }
  const float exs = (t > 0) ? ssum[t - 1] : 0.0f;
  float a[8], pm[8];
  float rm = -INFINITY;
#pragma unroll
  for (int i = 0; i < 8; ++i) {
    a[i] = xi[i] - (exs + ps[i]);
    rm = fmaxf(rm, a[i]);
    pm[i] = rm;
  }
  smax[t] = rm;
  __syncthreads();
  for (int st = 1; st < 256; st <<= 1) {
    float mv = (t >= st) ? smax[t - st] : -INFINITY;
    __syncthreads();
    smax[t] = fmaxf(smax[t], mv);
    __syncthreads();
  }
  const float exm = (t > 0) ? smax[t - 1] : -INFINITY;
#pragma unroll
  for (int i = 0; i < 8; ++i) {
    const float M = fmaxf(exm, pm[i]);
    const float F = exs + ps[i];
    av[base + s0 + i]  = a[i];
    Mv[base + s0 + i]  = M;
    nfv[base + s0 + i] = expf(-(F + M));
  }
}

// ---------- K3: V -> bf16 transposed global Vt[bh][d][s] --------------------
__global__ __launch_bounds__(256)
void vtrans_kernel(const float* __restrict__ v, unsigned short* __restrict__ vt)
{
  __shared__ float tile[64][68];
  const int st0 = blockIdx.x * 64, dt0 = blockIdx.y * 64;
  const int bh = blockIdx.z, b = bh >> 2, h = bh & 3;
  const int t = threadIdx.x;
#pragma unroll
  for (int i = 0; i < 4; ++i) {
    int u = t + 256 * i;
    int r = u >> 4, c4 = (u & 15) * 4;
    const float* p = v + ((size_t)(b * Sx) + st0 + r) * Hx + h * DHx + dt0 + c4;
    float4 vv = *(const float4*)p;
    tile[r][c4] = vv.x; tile[r][c4+1] = vv.y; tile[r][c4+2] = vv.z; tile[r][c4+3] = vv.w;
  }
  __syncthreads();
#pragma unroll
  for (int i = 0; i < 4; ++i) {
    int u = t + 256 * i;
    int dr = u >> 4, c4 = (u & 15) * 4;
    ushort4 o;
    o.x = f2bf(tile[c4+0][dr]); o.y = f2bf(tile[c4+1][dr]);
    o.z = f2bf(tile[c4+2][dr]); o.w = f2bf(tile[c4+3][dr]);
    *(ushort4*)(vt + ((size_t)bh * DHx + dt0 + dr) * Sx + st0 + c4) = o;
  }
}

// ---------- K4: flash mLSTM on MFMA, software-pipelined ----------------------
// 512 thr = 8 waves. BQ=32 q-rows per block, BK=64 keys per iter.
// QK role: wave (ks=w&3, qh=w>>2): 16-key slice x 16-q half; Q from LDS,
//   K frags from L2 (double-buffered in regs: next tile prefetched after QK).
// PV role: wave w: 32-d slice x 32 q; V frags loaded BEFORE QK (latency hidden
//   under QK+transform+barrier); P exchanged via double-buffered LDS.
constexpr int QSTR = 264;   // Qls row stride (bf16 elems)
constexpr int PSTR = 72;    // Pls row stride (64 keys + pad)

__global__ __launch_bounds__(512, 4)
void mlstm_mfma(const unsigned short* __restrict__ Qb,
                const unsigned short* __restrict__ Kb,
                const unsigned short* __restrict__ Vt,
                const float* __restrict__ av, const float* __restrict__ Mv,
                const float* __restrict__ nfv, const float* __restrict__ lnw,
                float* __restrict__ out)
{
  __shared__ __align__(16) unsigned short Qls[32 * QSTR];     // 16.9 KB
  __shared__ __align__(16) unsigned short Pls[2][32 * PSTR];  // 9.2 KB
  __shared__ float redRS[4][2][16];                           // 0.5 KB
  __shared__ float redS[8][2][16][2];                         // 2 KB

  const int bh = blockIdx.x, b = bh >> 2, h = bh & 3;
  const int ti = (int)gridDim.y - 1 - (int)blockIdx.y;   // big tiles first
  const int i0 = ti * 32;
  const int tid = threadIdx.x;
  const int w = tid >> 6, l = tid & 63;
  const int ks = w & 3, qh = w >> 2;
  const int lg = l >> 4, ll = l & 15;
  const size_t bhS = (size_t)bh * Sx;

  // stage Q tile (32 x 256) into LDS once
  {
    const int r = tid >> 4, c = (tid & 15) * 16;
    const unsigned short* qp = Qb + (bhS + i0 + r) * DHx + c;
    *(bf16x8*)&Qls[r * QSTR + c]     = *(const bf16x8*)qp;
    *(bf16x8*)&Qls[r * QSTR + c + 8] = *(const bf16x8*)(qp + 8);
  }
  const float Mq = Mv[bhS + i0 + qh * 16 + ll];

  f32x4 acc[2][2];   // [dt][qg]: d = w*32+dt*16+lg*4+r, q = qg*16+ll
#pragma unroll
  for (int dt = 0; dt < 2; ++dt)
#pragma unroll
    for (int qg = 0; qg < 2; ++qg) acc[dt][qg] = f32x4{0, 0, 0, 0};
  float rsum = 0.f;
  __syncthreads();

  const int nt = (i0 + 32 + 63) >> 6;
  const unsigned short* kbase = Kb + (bhS + ks * 16 + ll) * DHx + lg * 8;
  const unsigned short* vbase = Vt + ((size_t)bh * DHx + w * 32 + ll) * Sx + lg * 8;

  bf16x8 kA[8], kB[8];
#pragma unroll
  for (int d8 = 0; d8 < 8; ++d8) kA[d8] = *(const bf16x8*)(kbase + d8 * 32);

  auto body = [&](int tj, bf16x8 (&kc)[8], bf16x8 (&kn)[8]) {
    const int j0 = tj * 64;
    // gate coeffs for this key slice
    f32x4 a4 = *(const f32x4*)(av + bhS + j0 + ks * 16 + lg * 4);
    // V frags for current tile (consumed after barrier -> latency hidden)
    bf16x8 vf[2][2];
#pragma unroll
    for (int dt = 0; dt < 2; ++dt)
#pragma unroll
      for (int kap = 0; kap < 2; ++kap)
        vf[dt][kap] = *(const bf16x8*)(vbase + (size_t)dt * 16 * Sx + j0 + kap * 32);
    // ---- QK: 8 MFMA using current K frags ----
    f32x4 st = {0, 0, 0, 0};
    __builtin_amdgcn_s_setprio(1);
#pragma unroll
    for (int d8 = 0; d8 < 8; ++d8) {
      bf16x8 qf = *(const bf16x8*)&Qls[(qh * 16 + ll) * QSTR + d8 * 32 + lg * 8];
      st = __builtin_amdgcn_mfma_f32_16x16x32_bf16(kc[d8], qf, st, 0, 0, 0);
    }
    __builtin_amdgcn_s_setprio(0);
    // ---- prefetch next K tile (hidden under transform+barrier+PV) ----
    const int tn = (tj + 1 < nt) ? (tj + 1) : tj;
    const unsigned short* kp = kbase + ((size_t)tn * 64) * DHx;
#pragma unroll
    for (int d8 = 0; d8 < 8; ++d8) kn[d8] = *(const bf16x8*)(kp + d8 * 32);
    // ---- transform + P write ----
    const int qrow = i0 + qh * 16 + ll;
    const int k0i = j0 + ks * 16 + lg * 4;
    float p0 = (k0i + 0 <= qrow) ? st[0] * (RSQ * __expf(a4[0] - Mq)) : 0.f;
    float p1 = (k0i + 1 <= qrow) ? st[1] * (RSQ * __expf(a4[1] - Mq)) : 0.f;
    float p2 = (k0i + 2 <= qrow) ? st[2] * (RSQ * __expf(a4[2] - Mq)) : 0.f;
    float p3 = (k0i + 3 <= qrow) ? st[3] * (RSQ * __expf(a4[3] - Mq)) : 0.f;
    rsum += (p0 + p1) + (p2 + p3);
    *(uint2*)&Pls[tj & 1][(qh * 16 + ll) * PSTR + ks * 16 + lg * 4] =
        make_uint2(pk2bf(p0, p1), pk2bf(p2, p3));
    __syncthreads();
    // ---- PV: 8 MFMA, V from regs, P from LDS ----
    __builtin_amdgcn_s_setprio(1);
#pragma unroll
    for (int kap = 0; kap < 2; ++kap) {
      bf16x8 pf0 = *(const bf16x8*)&Pls[tj & 1][ll * PSTR + kap * 32 + lg * 8];
      bf16x8 pf1 = *(const bf16x8*)&Pls[tj & 1][(16 + ll) * PSTR + kap * 32 + lg * 8];
#pragma unroll
      for (int dt = 0; dt < 2; ++dt) {
        acc[dt][0] = __builtin_amdgcn_mfma_f32_16x16x32_bf16(vf[dt][kap], pf0, acc[dt][0], 0, 0, 0);
        acc[dt][1] = __builtin_amdgcn_mfma_f32_16x16x32_bf16(vf[dt][kap], pf1, acc[dt][1], 0, 0, 0);
      }
    }
    __builtin_amdgcn_s_setprio(0);
  };

  int tj = 0;
  while (true) {
    body(tj, kA, kB);
    if (++tj >= nt) break;
    body(tj, kB, kA);
    if (++tj >= nt) break;
  }

  // ---- cross-wave reductions ----
  {
    float rs = rsum;
    rs += __shfl_xor(rs, 16); rs += __shfl_xor(rs, 32);
    if (l < 16) redRS[ks][qh][l] = rs;
  }
#pragma unroll
  for (int qg = 0; qg < 2; ++qg) {
    float s1 = 0.f, s2 = 0.f;
#pragma unroll
    for (int dt = 0; dt < 2; ++dt)
#pragma unroll
      for (int r = 0; r < 4; ++r) {
        const float x = acc[dt][qg][r];
        s1 += x; s2 += x * x;
      }
    s1 += __shfl_xor(s1, 16); s1 += __shfl_xor(s1, 32);
    s2 += __shfl_xor(s2, 16); s2 += __shfl_xor(s2, 32);
    if (l < 16) { redS[w][qg][l][0] = s1; redS[w][qg][l][1] = s2; }
  }
  __syncthreads();

  // ---- epilogue: normalizer + group-LN, direct from accumulators ----
#pragma unroll
  for (int qg = 0; qg < 2; ++qg) {
    const int q = qg * 16 + ll;
    float rs = redRS[0][qg][ll] + redRS[1][qg][ll] + redRS[2][qg][ll] + redRS[3][qg][ll];
    float s1 = 0.f, s2 = 0.f;
#pragma unroll
    for (int wj = 0; wj < 8; ++wj) {
      s1 += redS[wj][qg][ll][0];
      s2 += redS[wj][qg][ll][1];
    }
    const float nf = nfv[bhS + i0 + q];
    const float inv = 1.f / (fmaxf(fabsf(rs), nf) + 1e-6f);
    const float mean = s1 * inv * (1.f / 256.f);
    const float ex2  = s2 * inv * inv * (1.f / 256.f);
    const float var  = ex2 - mean * mean;
    const float rstd = rsqrtf(var + 1e-5f);
    float* op = out + ((size_t)b * Sx + i0 + q) * Hx + h * DHx;
#pragma unroll
    for (int dt = 0; dt < 2; ++dt) {
      const int dbase = w * 32 + dt * 16 + lg * 4;
      f32x4 lw = *(const f32x4*)(lnw + h * DHx + dbase);
      float4 o;
      o.x = (acc[dt][qg][0] * inv - mean) * rstd * (1.f + lw[0]);
      o.y = (acc[dt][qg][1] * inv - mean) * rstd * (1.f + lw[1]);
      o.z = (acc[dt][qg][2] * inv - mean) * rstd * (1.f + lw[2]);
      o.w = (acc[dt][qg][3] * inv - mean) * rstd * (1.f + lw[3]);
      *(float4*)(op + dbase) = o;
    }
  }
}

extern "C" void kernel_launch(void* const* d_in, const int* in_sizes, int n_in,
                              void* d_out, int out_size, void* d_ws, size_t ws_size,
                              hipStream_t stream) {
  const float* q   = (const float*)d_in[0];
  const float* k   = (const float*)d_in[1];
  const float* v   = (const float*)d_in[2];
  const float* wi  = (const float*)d_in[3];
  const float* bi  = (const float*)d_in[4];
  const float* wf  = (const float*)d_in[5];
  const float* bf  = (const float*)d_in[6];
  const float* lnw = (const float*)d_in[7];
  float* out = (float*)d_out;
  float* ws  = (float*)d_ws;

  const int G = Bx * NHx * Sx;         // 16384
  float* ig  = ws;
  float* fg  = ws + (size_t)G;
  float* av  = ws + (size_t)2 * G;
  float* Mv  = ws + (size_t)3 * G;
  float* nfv = ws + (size_t)4 * G;
  unsigned short* Qb = (unsigned short*)(ws + (size_t)5 * G);
  unsigned short* Kb = Qb + (size_t)Bx * Sx * Hx;   // 4,194,304 elems
  unsigned short* Vt = Kb + (size_t)Bx * Sx * Hx;
  // total ws use: ~24.3 MB

  gates_kernel<<<Bx * Sx / 16, 512, 0, stream>>>(q, k, v, wi, bi, wf, bf, ig, fg, Qb, Kb);
  scan_kernel<<<Bx * NHx, 256, 0, stream>>>(ig, fg, av, Mv, nfv);
  dim3 gT(Sx / 64, DHx / 64, Bx * NHx);
  vtrans_kernel<<<gT, 256, 0, stream>>>(v, Vt);
  dim3 g4(Bx * NHx, Sx / 32);          // x = bh (XCD affinity), y = q-tile
  mlstm_mfma<<<g4, 512, 0, stream>>>(Qb, Kb, Vt, av, Mv, nfv, lnw, out);
}

// Round 7
// 171.038 us; speedup vs baseline: 1.0074x; 1.0074x over previous
//
#include <hip/hip_runtime.h>
#include <hip/hip_bf16.h>
#include <cstddef>

// Dims fixed by reference: B=2, S=2048, H=1024, NH=4, DH=256
constexpr int Bx = 2, Sx = 2048, Hx = 1024, NHx = 4, DHx = 256;
constexpr float RSQ = 0.0625f;   // 1/sqrt(256)

typedef __attribute__((ext_vector_type(8))) short    bf16x8;
typedef __attribute__((ext_vector_type(4))) float    f32x4;

__device__ __forceinline__ float logsigf(float x) {
  return (x >= 0.0f) ? -log1pf(expf(-x)) : x - log1pf(expf(x));
}
__device__ __forceinline__ unsigned short f2bf(float x) {  // RNE f32->bf16
  unsigned u = __builtin_bit_cast(unsigned, x);
  u = (u + 0x7fffu + ((u >> 16) & 1u)) >> 16;
  return (unsigned short)u;
}
__device__ __forceinline__ unsigned pk2bf(float a, float b) {
  return (unsigned)f2bf(a) | ((unsigned)f2bf(b) << 16);
}

// ---------- K1: gates (ig/fg) + bf16 side-copies of Q,K ---------------------
// 16 rows per block (512 thr = 8 waves, 2 rows/wave) to amortize W reads.
__global__ __launch_bounds__(512)
void gates_kernel(const float* __restrict__ q, const float* __restrict__ k,
                  const float* __restrict__ v,
                  const float* __restrict__ wi, const float* __restrict__ bi,
                  const float* __restrict__ wf, const float* __restrict__ bf,
                  float* __restrict__ ig, float* __restrict__ fg,
                  unsigned short* __restrict__ Qb, unsigned short* __restrict__ Kb)
{
  const int w = threadIdx.x >> 6, l = threadIdx.x & 63;
  const int bs0 = blockIdx.x * 16;
  const int bsr0 = bs0 + w * 2, bsr1 = bsr0 + 1;
  float p[2][8];
#pragma unroll
  for (int rr = 0; rr < 2; ++rr)
#pragma unroll
    for (int g2 = 0; g2 < 8; ++g2) p[rr][g2] = 0.f;

#pragma unroll
  for (int chunk = 0; chunk < 12; ++chunk) {
    const int idx = l * 4 + chunk * 256;     // 0..3071
    const float* src; int off;
    if (idx < 1024)       { src = q; off = idx; }
    else if (idx < 2048)  { src = k; off = idx - 1024; }
    else                  { src = v; off = idx - 2048; }
    float4 g0 = *(const float4*)(src + (size_t)bsr0 * Hx + off);
    float4 g1 = *(const float4*)(src + (size_t)bsr1 * Hx + off);
#pragma unroll
    for (int h = 0; h < 4; ++h) {
      float4 wiv = *(const float4*)(wi + h * 3 * Hx + idx);
      float4 wfv = *(const float4*)(wf + h * 3 * Hx + idx);
      p[0][h]     += g0.x*wiv.x + g0.y*wiv.y + g0.z*wiv.z + g0.w*wiv.w;
      p[1][h]     += g1.x*wiv.x + g1.y*wiv.y + g1.z*wiv.z + g1.w*wiv.w;
      p[0][4 + h] += g0.x*wfv.x + g0.y*wfv.y + g0.z*wfv.z + g0.w*wfv.w;
      p[1][4 + h] += g1.x*wfv.x + g1.y*wfv.y + g1.z*wfv.z + g1.w*wfv.w;
    }
    if (idx < 2048) {
      unsigned short* dst = (idx < 1024) ? Qb : Kb;
      const int hh = off >> 8, d = off & 255;
      const int b0 = bsr0 >> 11, s0p = bsr0 & 2047;
      const int b1 = bsr1 >> 11, s1p = bsr1 & 2047;
      ushort4 o0; o0.x=f2bf(g0.x); o0.y=f2bf(g0.y); o0.z=f2bf(g0.z); o0.w=f2bf(g0.w);
      ushort4 o1; o1.x=f2bf(g1.x); o1.y=f2bf(g1.y); o1.z=f2bf(g1.z); o1.w=f2bf(g1.w);
      *(ushort4*)(dst + ((size_t)(b0 * NHx + hh) * Sx + s0p) * DHx + d) = o0;
      *(ushort4*)(dst + ((size_t)(b1 * NHx + hh) * Sx + s1p) * DHx + d) = o1;
    }
  }
#pragma unroll
  for (int rr = 0; rr < 2; ++rr)
#pragma unroll
    for (int g2 = 0; g2 < 8; ++g2) {
      float x = p[rr][g2];
      x += __shfl_xor(x, 1);  x += __shfl_xor(x, 2);  x += __shfl_xor(x, 4);
      x += __shfl_xor(x, 8);  x += __shfl_xor(x, 16); x += __shfl_xor(x, 32);
      p[rr][g2] = x;
    }
  if (l == 0) {
#pragma unroll
    for (int rr = 0; rr < 2; ++rr) {
      const int bs = bs0 + w * 2 + rr;
      const int b = bs >> 11, spos = bs & 2047;
#pragma unroll
      for (int h = 0; h < 4; ++h) {
        ig[(size_t)(b * NHx + h) * Sx + spos] = p[rr][h] + bi[h];
        fg[(size_t)(b * NHx + h) * Sx + spos] = p[rr][4 + h] + bf[h];
      }
    }
  }
}

// ---------- K2: per-(b,h) scan: a[], M[], exp(-m)[] -------------------------
__global__ __launch_bounds__(256)
void scan_kernel(const float* __restrict__ ig, const float* __restrict__ fg,
                 float* __restrict__ av, float* __restrict__ Mv,
                 float* __restrict__ nfv)
{
  const int bh = blockIdx.x;
  const int t  = threadIdx.x;
  const size_t base = (size_t)bh * Sx;
  const int s0 = t * 8;
  float4 f0 = *(const float4*)(fg + base + s0);
  float4 f1 = *(const float4*)(fg + base + s0 + 4);
  float4 g0 = *(const float4*)(ig + base + s0);
  float4 g1 = *(const float4*)(ig + base + s0 + 4);
  float xf[8] = {f0.x,f0.y,f0.z,f0.w,f1.x,f1.y,f1.z,f1.w};
  float xi[8] = {g0.x,g0.y,g0.z,g0.w,g1.x,g1.y,g1.z,g1.w};
  float ps[8];
  float run = 0.0f;
#pragma unroll
  for (int i = 0; i < 8; ++i) { run += logsigf(xf[i]); ps[i] = run; }
  __shared__ float ssum[256];
  __shared__ float smax[256];
  ssum[t] = run;
  __syncthreads();
  for (int st = 1; st < 256; st <<= 1) {
    float addv = (t >= st) ? ssum[t - st] : 0.0f;
    __syncthreads();
    ssum[t] += addv;
    __syncthreads();
  }
  const float exs = (t > 0) ? ssum[t - 1] : 0.0f;
  float a[8], pm[8];
  float rm = -INFINITY;
#pragma unroll
  for (int i = 0; i < 8; ++i) {
    a[i] = xi[i] - (exs + ps[i]);
    rm = fmaxf(rm, a[i]);
    pm[i] = rm;
  }
  smax[t] = rm;
  __syncthreads();
  for (int st = 1; st < 256; st <<= 1) {
    float mv = (t >= st) ? smax[t - st] : -INFINITY;
    __syncthreads();
    smax[t] = fmaxf(smax[t], mv);
    __syncthreads();
  }
  const float exm = (t > 0) ? smax[t - 1] : -INFINITY;
#pragma unroll
  for (int i = 0; i < 8; ++i) {
    const float M = fmaxf(exm, pm[i]);
    const float F = exs + ps[i];
    av[base + s0 + i]  = a[i];
    Mv[base + s0 + i]  = M;
    nfv[base + s0 + i] = expf(-(F + M));
  }
}

// ---------- K3: V -> bf16 transposed global Vt[bh][d][s] --------------------
__global__ __launch_bounds__(256)
void vtrans_kernel(const float* __restrict__ v, unsigned short* __restrict__ vt)
{
  __shared__ float tile[64][68];
  const int st0 = blockIdx.x * 64, dt0 = blockIdx.y * 64;
  const int bh = blockIdx.z, b = bh >> 2, h = bh & 3;
  const int t = threadIdx.x;
#pragma unroll
  for (int i = 0; i < 4; ++i) {
    int u = t + 256 * i;
    int r = u >> 4, c4 = (u & 15) * 4;
    const float* p = v + ((size_t)(b * Sx) + st0 + r) * Hx + h * DHx + dt0 + c4;
    float4 vv = *(const float4*)p;
    tile[r][c4] = vv.x; tile[r][c4+1] = vv.y; tile[r][c4+2] = vv.z; tile[r][c4+3] = vv.w;
  }
  __syncthreads();
#pragma unroll
  for (int i = 0; i < 4; ++i) {
    int u = t + 256 * i;
    int dr = u >> 4, c4 = (u & 15) * 4;
    ushort4 o;
    o.x = f2bf(tile[c4+0][dr]); o.y = f2bf(tile[c4+1][dr]);
    o.z = f2bf(tile[c4+2][dr]); o.w = f2bf(tile[c4+3][dr]);
    *(ushort4*)(vt + ((size_t)bh * DHx + dt0 + dr) * Sx + st0 + c4) = o;
  }
}

// ---------- K4: flash mLSTM on MFMA, software-pipelined ----------------------
// 512 thr = 8 waves. BQ=32 q-rows per block, BK=64 keys per iter.
// QK role: wave (ks=w&3, qh=w>>2): 16-key slice x 16-q half; Q from LDS,
//   K frags from L2 (double-buffered in regs: next tile prefetched after QK).
// PV role: wave w: 32-d slice x 32 q; V frags loaded BEFORE QK (latency hidden
//   under QK+transform+barrier); P exchanged via double-buffered LDS.
constexpr int QSTR = 264;   // Qls row stride (bf16 elems)
constexpr int PSTR = 72;    // Pls row stride (64 keys + pad)

__global__ __launch_bounds__(512, 4)
void mlstm_mfma(const unsigned short* __restrict__ Qb,
                const unsigned short* __restrict__ Kb,
                const unsigned short* __restrict__ Vt,
                const float* __restrict__ av, const float* __restrict__ Mv,
                const float* __restrict__ nfv, const float* __restrict__ lnw,
                float* __restrict__ out)
{
  __shared__ __align__(16) unsigned short Qls[32 * QSTR];     // 16.9 KB
  __shared__ __align__(16) unsigned short Pls[2][32 * PSTR];  // 9.2 KB
  __shared__ float redRS[4][2][16];                           // 0.5 KB
  __shared__ float redS[8][2][16][2];                         // 2 KB

  const int bh = blockIdx.x, b = bh >> 2, h = bh & 3;
  const int ti = (int)gridDim.y - 1 - (int)blockIdx.y;   // big tiles first
  const int i0 = ti * 32;
  const int tid = threadIdx.x;
  const int w = tid >> 6, l = tid & 63;
  const int ks = w & 3, qh = w >> 2;
  const int lg = l >> 4, ll = l & 15;
  const size_t bhS = (size_t)bh * Sx;

  // stage Q tile (32 x 256) into LDS once
  {
    const int r = tid >> 4, c = (tid & 15) * 16;
    const unsigned short* qp = Qb + (bhS + i0 + r) * DHx + c;
    *(bf16x8*)&Qls[r * QSTR + c]     = *(const bf16x8*)qp;
    *(bf16x8*)&Qls[r * QSTR + c + 8] = *(const bf16x8*)(qp + 8);
  }
  const float Mq = Mv[bhS + i0 + qh * 16 + ll];

  f32x4 acc[2][2];   // [dt][qg]: d = w*32+dt*16+lg*4+r, q = qg*16+ll
#pragma unroll
  for (int dt = 0; dt < 2; ++dt)
#pragma unroll
    for (int qg = 0; qg < 2; ++qg) acc[dt][qg] = f32x4{0, 0, 0, 0};
  float rsum = 0.f;
  __syncthreads();

  const int nt = (i0 + 32 + 63) >> 6;
  const unsigned short* kbase = Kb + (bhS + ks * 16 + ll) * DHx + lg * 8;
  const unsigned short* vbase = Vt + ((size_t)bh * DHx + w * 32 + ll) * Sx + lg * 8;

  bf16x8 kA[8], kB[8];
#pragma unroll
  for (int d8 = 0; d8 < 8; ++d8) kA[d8] = *(const bf16x8*)(kbase + d8 * 32);

  auto body = [&](int tj, bf16x8 (&kc)[8], bf16x8 (&kn)[8]) {
    const int j0 = tj * 64;
    // gate coeffs for this key slice
    f32x4 a4 = *(const f32x4*)(av + bhS + j0 + ks * 16 + lg * 4);
    // V frags for current tile (consumed after barrier -> latency hidden)
    bf16x8 vf[2][2];
#pragma unroll
    for (int dt = 0; dt < 2; ++dt)
#pragma unroll
      for (int kap = 0; kap < 2; ++kap)
        vf[dt][kap] = *(const bf16x8*)(vbase + (size_t)dt * 16 * Sx + j0 + kap * 32);
    // ---- QK: 8 MFMA using current K frags ----
    f32x4 st = {0, 0, 0, 0};
    __builtin_amdgcn_s_setprio(1);
#pragma unroll
    for (int d8 = 0; d8 < 8; ++d8) {
      bf16x8 qf = *(const bf16x8*)&Qls[(qh * 16 + ll) * QSTR + d8 * 32 + lg * 8];
      st = __builtin_amdgcn_mfma_f32_16x16x32_bf16(kc[d8], qf, st, 0, 0, 0);
    }
    __builtin_amdgcn_s_setprio(0);
    // ---- prefetch next K tile (hidden under transform+barrier+PV) ----
    const int tn = (tj + 1 < nt) ? (tj + 1) : tj;
    const unsigned short* kp = kbase + ((size_t)tn * 64) * DHx;
#pragma unroll
    for (int d8 = 0; d8 < 8; ++d8) kn[d8] = *(const bf16x8*)(kp + d8 * 32);
    // ---- transform + P write ----
    const int qrow = i0 + qh * 16 + ll;
    const int k0i = j0 + ks * 16 + lg * 4;
    float p0 = (k0i + 0 <= qrow) ? st[0] * (RSQ * __expf(a4[0] - Mq)) : 0.f;
    float p1 = (k0i + 1 <= qrow) ? st[1] * (RSQ * __expf(a4[1] - Mq)) : 0.f;
    float p2 = (k0i + 2 <= qrow) ? st[2] * (RSQ * __expf(a4[2] - Mq)) : 0.f;
    float p3 = (k0i + 3 <= qrow) ? st[3] * (RSQ * __expf(a4[3] - Mq)) : 0.f;
    rsum += (p0 + p1) + (p2 + p3);
    *(uint2*)&Pls[tj & 1][(qh * 16 + ll) * PSTR + ks * 16 + lg * 4] =
        make_uint2(pk2bf(p0, p1), pk2bf(p2, p3));
    __syncthreads();
    // ---- PV: 8 MFMA, V from regs, P from LDS ----
    __builtin_amdgcn_s_setprio(1);
#pragma unroll
    for (int kap = 0; kap < 2; ++kap) {
      bf16x8 pf0 = *(const bf16x8*)&Pls[tj & 1][ll * PSTR + kap * 32 + lg * 8];
      bf16x8 pf1 = *(const bf16x8*)&Pls[tj & 1][(16 + ll) * PSTR + kap * 32 + lg * 8];
#pragma unroll
      for (int dt = 0; dt < 2; ++dt) {
        acc[dt][0] = __builtin_amdgcn_mfma_f32_16x16x32_bf16(vf[dt][kap], pf0, acc[dt][0], 0, 0, 0);
        acc[dt][1] = __builtin_amdgcn_mfma_f32_16x16x32_bf16(vf[dt][kap], pf1, acc[dt][1], 0, 0, 0);
      }
    }
    __builtin_amdgcn_s_setprio(0);
  };

  int tj = 0;
  while (true) {
    body(tj, kA, kB);
    if (++tj >= nt) break;
    body(tj, kB, kA);
    if (++tj >= nt) break;
  }

  // ---- cross-wave reductions ----
  {
    float rs = rsum;
    rs += __shfl_xor(rs, 16); rs += __shfl_xor(rs, 32);
    if (l < 16) redRS[ks][qh][l] = rs;
  }
#pragma unroll
  for (int qg = 0; qg < 2; ++qg) {
    float s1 = 0.f, s2 = 0.f;
#pragma unroll
    for (int dt = 0; dt < 2; ++dt)
#pragma unroll
      for (int r = 0; r < 4; ++r) {
        const float x = acc[dt][qg][r];
        s1 += x; s2 += x * x;
      }
    s1 += __shfl_xor(s1, 16); s1 += __shfl_xor(s1, 32);
    s2 += __shfl_xor(s2, 16); s2 += __shfl_xor(s2, 32);
    if (l < 16) { redS[w][qg][l][0] = s1; redS[w][qg][l][1] = s2; }
  }
  __syncthreads();

  // ---- epilogue: normalizer + group-LN, direct from accumulators ----
#pragma unroll
  for (int qg = 0; qg < 2; ++qg) {
    const int q = qg * 16 + ll;
    float rs = redRS[0][qg][ll] + redRS[1][qg][ll] + redRS[2][qg][ll] + redRS[3][qg][ll];
    float s1 = 0.f, s2 = 0.f;
#pragma unroll
    for (int wj = 0; wj < 8; ++wj) {
      s1 += redS[wj][qg][ll][0];
      s2 += redS[wj][qg][ll][1];
    }
    const float nf = nfv[bhS + i0 + q];
    const float inv = 1.f / (fmaxf(fabsf(rs), nf) + 1e-6f);
    const float mean = s1 * inv * (1.f / 256.f);
    const float ex2  = s2 * inv * inv * (1.f / 256.f);
    const float var  = ex2 - mean * mean;
    const float rstd = rsqrtf(var + 1e-5f);
    float* op = out + ((size_t)b * Sx + i0 + q) * Hx + h * DHx;
#pragma unroll
    for (int dt = 0; dt < 2; ++dt) {
      const int dbase = w * 32 + dt * 16 + lg * 4;
      f32x4 lw = *(const f32x4*)(lnw + h * DHx + dbase);
      float4 o;
      o.x = (acc[dt][qg][0] * inv - mean) * rstd * (1.f + lw[0]);
      o.y = (acc[dt][qg][1] * inv - mean) * rstd * (1.f + lw[1]);
      o.z = (acc[dt][qg][2] * inv - mean) * rstd * (1.f + lw[2]);
      o.w = (acc[dt][qg][3] * inv - mean) * rstd * (1.f + lw[3]);
      *(float4*)(op + dbase) = o;
    }
  }
}

extern "C" void kernel_launch(void* const* d_in, const int* in_sizes, int n_in,
                              void* d_out, int out_size, void* d_ws, size_t ws_size,
                              hipStream_t stream) {
  const float* q   = (const float*)d_in[0];
  const float* k   = (const float*)d_in[1];
  const float* v   = (const float*)d_in[2];
  const float* wi  = (const float*)d_in[3];
  const float* bi  = (const float*)d_in[4];
  const float* wf  = (const float*)d_in[5];
  const float* bf  = (const float*)d_in[6];
  const float* lnw = (const float*)d_in[7];
  float* out = (float*)d_out;
  float* ws  = (float*)d_ws;

  const int G = Bx * NHx * Sx;         // 16384
  float* ig  = ws;
  float* fg  = ws + (size_t)G;
  float* av  = ws + (size_t)2 * G;
  float* Mv  = ws + (size_t)3 * G;
  float* nfv = ws + (size_t)4 * G;
  unsigned short* Qb = (unsigned short*)(ws + (size_t)5 * G);
  unsigned short* Kb = Qb + (size_t)Bx * Sx * Hx;   // 4,194,304 elems
  unsigned short* Vt = Kb + (size_t)Bx * Sx * Hx;
  // total ws use: ~24.3 MB

  gates_kernel<<<Bx * Sx / 16, 512, 0, stream>>>(q, k, v, wi, bi, wf, bf, ig, fg, Qb, Kb);
  scan_kernel<<<Bx * NHx, 256, 0, stream>>>(ig, fg, av, Mv, nfv);
  dim3 gT(Sx / 64, DHx / 64, Bx * NHx);
  vtrans_kernel<<<gT, 256, 0, stream>>>(v, Vt);
  dim3 g4(Bx * NHx, Sx / 32);          // x = bh (XCD affinity), y = q-tile
  mlstm_mfma<<<g4, 512, 0, stream>>>(Qb, Kb, Vt, av, Mv, nfv, lnw, out);
}